// Round 8
// baseline (522.529 us; speedup 1.0000x reference)
//
#include <hip/hip_runtime.h>
#include <cstdint>
#include <cstddef>

#define B_ 64
#define S_ 8
#define D_ 2048
#define V_ 128000
#define CAND_CAP 8192
#define NBLK 500            // V_/256 GEMM blocks

typedef __bf16 v8bf __attribute__((ext_vector_type(8)));
typedef float  v4f  __attribute__((ext_vector_type(4)));

#define GLOBAL_AS __attribute__((address_space(1)))
#define LDS_AS    __attribute__((address_space(3)))

__device__ __forceinline__ void gload_lds16(const float* g, float* l){
  __builtin_amdgcn_global_load_lds((const GLOBAL_AS uint32_t*)g, (LDS_AS uint32_t*)l, 16, 0, 0);
}

// ---------------- threefry2x32 (JAX-compatible) ----------------
__device__ __forceinline__ uint32_t rotl32(uint32_t x, int r){ return (x << r) | (x >> (32 - r)); }
__device__ __forceinline__ void tfround(uint32_t& x0, uint32_t& x1, int r){
  x0 += x1; x1 = rotl32(x1, r); x1 ^= x0;
}
__device__ __forceinline__ void threefry2x32(uint32_t k0, uint32_t k1, uint32_t c0, uint32_t c1,
                                             uint32_t& o0, uint32_t& o1){
  uint32_t ks2 = k0 ^ k1 ^ 0x1BD11BDAu;
  uint32_t x0 = c0 + k0, x1 = c1 + k1;
  tfround(x0,x1,13); tfround(x0,x1,15); tfround(x0,x1,26); tfround(x0,x1,6);
  x0 += k1; x1 += ks2 + 1u;
  tfround(x0,x1,17); tfround(x0,x1,29); tfround(x0,x1,16); tfround(x0,x1,24);
  x0 += ks2; x1 += k0 + 2u;
  tfround(x0,x1,13); tfround(x0,x1,15); tfround(x0,x1,26); tfround(x0,x1,6);
  x0 += k0; x1 += k1 + 3u;
  tfround(x0,x1,17); tfround(x0,x1,29); tfround(x0,x1,16); tfround(x0,x1,24);
  x0 += k1; x1 += ks2 + 4u;
  tfround(x0,x1,13); tfround(x0,x1,15); tfround(x0,x1,26); tfround(x0,x1,6);
  x0 += ks2; x1 += k0 + 5u;
  o0 = x0; o1 = x1;
}

#define JAX_PARTITIONABLE 1

__device__ __forceinline__ float gumbel_at(uint32_t b, uint32_t v){
  uint32_t j = b * (uint32_t)V_ + v;
  uint32_t bits;
#if JAX_PARTITIONABLE
  uint32_t o0, o1; threefry2x32(0u, 42u, 0u, j, o0, o1);
  bits = o0 ^ o1;
#else
  const uint32_t HALF = 4096000u;  // B*V/2
  uint32_t o0, o1;
  if (j < HALF){ threefry2x32(0u, 42u, j, j + HALF, o0, o1); bits = o0; }
  else        { threefry2x32(0u, 42u, j - HALF, j, o0, o1); bits = o1; }
#endif
  uint32_t fb = (bits >> 9) | 0x3F800000u;
  float f = __uint_as_float(fb) - 1.0f;
  const float TINY = 1.17549435e-38f;
  float u = fmaxf(TINY, f + TINY);
  return -logf(-logf(u));
}

__device__ __forceinline__ unsigned ordkey(float f){
  unsigned u = __float_as_uint(f);
  return (u & 0x80000000u) ? ~u : (u | 0x80000000u);
}
__device__ __forceinline__ float ordinv(unsigned o){
  unsigned u = (o & 0x80000000u) ? (o & 0x7FFFFFFFu) : ~o;
  return __uint_as_float(u);
}

__device__ __forceinline__ v8bf ld_bf8(const unsigned short* p){
  uint4 u = *reinterpret_cast<const uint4*>(p);
  return __builtin_bit_cast(v8bf, u);
}

// ---------------- kernels ----------------

// gather h at out_pos, split fp32 -> bf16 hi/lo in FRAGMENT-PACKED layout:
// Apk[(((s*4 + mi)*64) + kg*16 + r16)*8 + j], s = k>>5, kg=(k>>3)&3, j=k&7, mi=b>>4, r16=b&15
__global__ __launch_bounds__(256) void Sampler_gather(const float* __restrict__ x,
    const int* __restrict__ out_pos, unsigned short* __restrict__ hhi,
    unsigned short* __restrict__ hlo, unsigned* __restrict__ cnt,
    unsigned* __restrict__ Mo){
  const int pos = out_pos[0];
  int i = blockIdx.x * 256 + threadIdx.x;
  if (i < B_ * D_){
    int bq = i >> 11;          // b
    int kq = i & 2047;         // k
    float v = x[((size_t)bq * S_ + pos) * D_ + kq];
    __bf16 hb = (__bf16)v;
    float hf = (float)hb;
    __bf16 lb = (__bf16)(v - hf);
    int s  = kq >> 5;
    int kg = (kq >> 3) & 3;
    int j  = kq & 7;
    int mi = bq >> 4;
    int r16 = bq & 15;
    int idx = (((s * 4 + mi) * 64) + kg * 16 + r16) * 8 + j;
    hhi[idx] = __builtin_bit_cast(unsigned short, hb);
    hlo[idx] = __builtin_bit_cast(unsigned short, lb);
  }
  if (i < 64){ cnt[i] = 0; Mo[i] = 0; }
}

// Split-bf16 MFMA GEMM, R6 geometry (BN=256, BK=32, XOR-swizzled stage+read,
// packed A) with DEEP PIPELINE: 4 LDS buffers, stage prefetch depth 3, A-reg
// prefetch depth 2, counted s_waitcnt vmcnt(16) + raw s_barrier per chunk
// (never drains to 0 in the loop -> HBM queue never empties).
__global__ __launch_bounds__(256, 1) void Sampler_gemm(
    const unsigned short* __restrict__ hhi,  // packed A hi
    const unsigned short* __restrict__ hlo,  // packed A lo
    const float* __restrict__ emb,           // [V_][D_]
    const float* __restrict__ bias,          // [V_]
    float* __restrict__ out)                 // [64][V_]
{
  __shared__ float Bs[4][256 * 32];          // 4 x 32 KB = 128 KB -> 1 block/CU
  const int tid  = threadIdx.x;
  const int wid  = tid >> 6;
  const int lane = tid & 63;
  const int r16  = lane & 15;
  const int kg   = lane >> 4;                // 0..3
  const int vbase = (blockIdx.x << 8) + (wid << 6);

  // staging constants: thread t stages dst bytes t*16 + p*4096 (p=0..7)
  const int srow = tid >> 3;                 // row within 32-row p-group
  const int hsrc = (tid & 7) ^ (srow & 7);   // inverse-swizzled source granule
  const float* sbase = emb + (size_t)((blockIdx.x << 8) + srow) * D_ + hsrc * 4;

  // read constants: phys granules for this lane's k-slice (row&7 == r16&7)
  const int h0 = ((2 * kg)     ^ (r16 & 7)) * 4;  // in floats
  const int h1 = ((2 * kg + 1) ^ (r16 & 7)) * 4;

  v4f acc[4][4];
#pragma unroll
  for (int mi = 0; mi < 4; ++mi)
#pragma unroll
    for (int ni = 0; ni < 4; ++ni) acc[mi][ni] = (v4f){0.f, 0.f, 0.f, 0.f};

  const unsigned short* hhb = hhi + lane * 8;
  const unsigned short* hlb = hlo + lane * 8;

  v8bf ah0[4], al0[4], ah1[4], al1[4];       // A-reg double set (parity c&1)

  auto LDA = [&](int c, v8bf (&ah)[4], v8bf (&al)[4]){
#pragma unroll
    for (int mi = 0; mi < 4; ++mi){
      const int fo = (c * 4 + mi) * 512;     // chunk stride 2048, mi stride 512
      ah[mi] = ld_bf8(hhb + fo);
      al[mi] = ld_bf8(hlb + fo);
    }
  };
  auto STAGE = [&](int c){
    float* dst = &Bs[c & 3][tid * 4];
    const float* src = sbase + c * 32;
#pragma unroll
    for (int p = 0; p < 8; ++p)
      gload_lds16(src + (size_t)p * 32 * D_, dst + p * 1024);
  };
  auto COMPUTE = [&](int c, v8bf (&ah)[4], v8bf (&al)[4]){
    const float* bbase = &Bs[c & 3][0];
#pragma unroll
    for (int ni = 0; ni < 4; ++ni){
      const int r = (wid << 6) + (ni << 4) + r16;
      const float* bp = bbase + r * 32;
      float4 b0 = *(const float4*)(bp + h0);   // k = 8kg .. +3
      float4 b1 = *(const float4*)(bp + h1);   // k = 8kg+4 .. +7
      float xf[8] = { b0.x, b0.y, b0.z, b0.w, b1.x, b1.y, b1.z, b1.w };
      v8bf bh, bl;
#pragma unroll
      for (int j = 0; j < 8; ++j){
        float v = xf[j];
        __bf16 hb = (__bf16)v;
        float hf = (float)hb;
        bh[j] = hb;
        bl[j] = (__bf16)(v - hf);
      }
#pragma unroll
      for (int mi = 0; mi < 4; ++mi){
        acc[mi][ni] = __builtin_amdgcn_mfma_f32_16x16x32_bf16(ah[mi], bh, acc[mi][ni], 0, 0, 0);
        acc[mi][ni] = __builtin_amdgcn_mfma_f32_16x16x32_bf16(al[mi], bh, acc[mi][ni], 0, 0, 0);
        acc[mi][ni] = __builtin_amdgcn_mfma_f32_16x16x32_bf16(ah[mi], bl, acc[mi][ni], 0, 0, 0);
      }
    }
  };

  // prologue: issue order fixed: stage(0), A(0), stage(1), A(1), stage(2)
  STAGE(0); LDA(0, ah0, al0); STAGE(1); LDA(1, ah1, al1); STAGE(2);

#pragma unroll 1
  for (int c = 0; c < 64; ++c){
    // own-wave counted wait: retires through A(c) (and stage(c), older);
    // leaves stage(c+1..c+2/3) + A(c+1) in flight.
    asm volatile("s_waitcnt vmcnt(16)" ::: "memory");
    __builtin_amdgcn_sched_barrier(0);
    __builtin_amdgcn_s_barrier();            // all waves' stage(c) shares done
    if (c + 3 < 64) STAGE(c + 3);            // writes buf (c-1)&3: all waves past compute(c-1)
    if ((c & 1) == 0){
      COMPUTE(c, ah0, al0);
      if (c + 2 < 64) LDA(c + 2, ah0, al0);  // WAR on regs keeps this after COMPUTE
    } else {
      COMPUTE(c, ah1, al1);
      if (c + 2 < 64) LDA(c + 2, ah1, al1);
    }
  }

  // epilogue: + bias
#pragma unroll
  for (int ni = 0; ni < 4; ++ni){
    const int v = vbase + 16 * ni + r16;
    const float bv = bias[v];
#pragma unroll
    for (int mi = 0; mi < 4; ++mi){
#pragma unroll
      for (int r = 0; r < 4; ++r){
        const int b = 16 * mi + 4 * kg + r;
        out[(size_t)b * V_ + v] = acc[mi][ni][r] + bv;
      }
    }
  }
}

// per-row max via 4 column-slices per row, atomicMax on ordkey
__global__ __launch_bounds__(256) void Sampler_rowmax(const float* __restrict__ logits,
    unsigned* __restrict__ Mo){
  __shared__ float red[4];
  const int b = blockIdx.x >> 2, sl = blockIdx.x & 3;
  const int tid = threadIdx.x;
  const float4* row = (const float4*)(logits + (size_t)b * V_ + sl * 32000);
  float m = -3.4e38f;
  for (int i = tid; i < 8000; i += 256){
    float4 v = row[i];
    m = fmaxf(m, fmaxf(fmaxf(v.x, v.y), fmaxf(v.z, v.w)));
  }
#pragma unroll
  for (int off = 32; off; off >>= 1) m = fmaxf(m, __shfl_down(m, off));
  if ((tid & 63) == 0) red[tid >> 6] = m;
  __syncthreads();
  if (tid == 0){
    m = fmaxf(fmaxf(red[0], red[1]), fmaxf(red[2], red[3]));
    atomicMax(&Mo[b], ordkey(m));
  }
}

// fused: deterministic per-slice softmax-denom partials + atomic-free candidate
// collect (l > M - 1.75) via ballot compaction; one global atomicAdd per block.
__global__ __launch_bounds__(256) void Sampler_collectZ(const float* __restrict__ logits,
    const unsigned* __restrict__ Mo, float* __restrict__ Mb, float* __restrict__ Zp,
    unsigned* __restrict__ cnt, float* __restrict__ cval, unsigned* __restrict__ cidx){
  __shared__ float    sv[4][1024];
  __shared__ unsigned si[4][1024];
  __shared__ unsigned wcnt_s[4];
  __shared__ unsigned gbase_s;
  __shared__ float red[4];
  const int b = blockIdx.x >> 2, sl = blockIdx.x & 3;
  const int tid = threadIdx.x, wid = tid >> 6, lane = tid & 63;
  const float M = ordinv(Mo[b]);
  const float T = M - 1.75f;
  const int base = sl * 32000;
  const float4* row = (const float4*)(logits + (size_t)b * V_ + base);
  unsigned wcnt = 0;
  float z = 0.f;
  for (int i = tid; i < 8000; i += 256){     // 8000 = 31*256 + 64: tails wave-uniform
    float4 v = row[i];
    z += expf(v.x - M); z += expf(v.y - M);
    z += expf(v.z - M); z += expf(v.w - M);
    float vv[4] = {v.x, v.y, v.z, v.w};
    const unsigned idx0 = (unsigned)(base + i * 4);
#pragma unroll
    for (int j = 0; j < 4; ++j){
      bool q = vv[j] > T;
      unsigned long long mask = __ballot(q);
      if (q){
        unsigned slot = wcnt + (unsigned)__popcll(mask & ((1ull << lane) - 1ull));
        if (slot < 1024u){ sv[wid][slot] = vv[j]; si[wid][slot] = idx0 + j; }
      }
      wcnt += (unsigned)__popcll(mask);
    }
  }
  // deterministic Z partial (fixed shuffle order)
#pragma unroll
  for (int off = 32; off; off >>= 1) z += __shfl_down(z, off);
  if (lane == 0){ red[wid] = z; wcnt_s[wid] = wcnt < 1024u ? wcnt : 1024u; }
  __syncthreads();
  if (tid == 0){
    Zp[b * 4 + sl] = ((red[0] + red[1]) + red[2]) + red[3];
    if (sl == 0) Mb[b] = M;
    gbase_s = atomicAdd(&cnt[b], wcnt_s[0] + wcnt_s[1] + wcnt_s[2] + wcnt_s[3]);
  }
  __syncthreads();
  unsigned pre = gbase_s;
  for (int w = 0; w < 4; ++w){ if (w == wid) break; pre += wcnt_s[w]; }
  const unsigned myn = wcnt_s[wid];
  for (unsigned i = lane; i < myn; i += 64){
    unsigned pos = pre + i;
    if (pos < CAND_CAP){
      cval[b * CAND_CAP + pos] = sv[wid][i];
      cidx[b * CAND_CAP + pos] = si[wid][i];
    }
  }
}

// extract top-K (stable: value desc, index asc) by iterative argmax over candidates
__global__ __launch_bounds__(256) void Sampler_topk(const unsigned* __restrict__ cnt,
    const float* __restrict__ cval, const unsigned* __restrict__ cidx,
    const int* __restrict__ top_ks, float* __restrict__ tv, unsigned* __restrict__ ti,
    unsigned* __restrict__ kef){
  __shared__ unsigned long long keys[CAND_CAP];
  __shared__ unsigned long long red[4];
  const int b = blockIdx.x;
  const int tid = threadIdx.x;
  int n = (int)min(cnt[b], (unsigned)CAND_CAP);
  const int nr = (n + 255) & ~255;           // scan bound, multiple of 256
  for (int i = tid; i < nr; i += 256){
    unsigned long long kk = 0ull;
    if (i < n){
      unsigned o = ordkey(cval[b * CAND_CAP + i]);
      kk = ((unsigned long long)o << 32) | (unsigned long long)(0xFFFFFFFFu - cidx[b * CAND_CAP + i]);
    }
    keys[i] = kk;
  }
  __syncthreads();
  int K = top_ks[b];
  K = K < 1 ? 1 : (K > 63 ? 63 : K);
  K = K < n ? K : n;
  for (int k = 0; k < K; ++k){
    unsigned long long best = 0ull;
    for (int i = tid; i < nr; i += 256){
      unsigned long long xx = keys[i];
      best = xx > best ? xx : best;
    }
#pragma unroll
    for (int off = 32; off; off >>= 1){
      unsigned long long o = __shfl_down(best, off);
      best = o > best ? o : best;
    }
    if ((tid & 63) == 0) red[tid >> 6] = best;
    __syncthreads();
    {
      unsigned long long m01 = red[0] > red[1] ? red[0] : red[1];
      unsigned long long m23 = red[2] > red[3] ? red[2] : red[3];
      best = m01 > m23 ? m01 : m23;
    }
    for (int i = tid; i < nr; i += 256)
      if (keys[i] == best) keys[i] = 0ull;
    if (tid == 0){
      tv[b * 64 + k] = ordinv((unsigned)(best >> 32));
      ti[b * 64 + k] = 0xFFFFFFFFu - (unsigned)(best & 0xFFFFFFFFu);
    }
    __syncthreads();
  }
  if (tid == 0) kef[b] = (unsigned)K;
}

// top-p mask on sorted list + gumbel argmax -> token (written as float)
__global__ __launch_bounds__(64) void Sampler_sample(const float* __restrict__ tv,
    const unsigned* __restrict__ ti, const unsigned* __restrict__ kef,
    const float* __restrict__ Mb, const float* __restrict__ Zp,
    const float* __restrict__ top_ps, float* __restrict__ out_tok){
  const int b = blockIdx.x;
  const int k = threadIdx.x;
  const int K = (int)kef[b];
  const float M = Mb[b], tp = top_ps[b];
  const float Z = ((Zp[b * 4 + 0] + Zp[b * 4 + 1]) + Zp[b * 4 + 2]) + Zp[b * 4 + 3];
  float p = 0.f, lv = 0.f; unsigned iv = 0xFFFFFFFFu;
  if (k < K){
    lv = tv[b * 64 + k];
    iv = ti[b * 64 + k];
    p = expf(lv - M) / Z;
  }
  float incl = p;
#pragma unroll
  for (int off = 1; off < 64; off <<= 1){
    float t = __shfl_up(incl, off);
    if (k >= off) incl += t;
  }
  float excl = incl - p;
  float val = -3.4e38f; unsigned idx = 0xFFFFFFFFu;
  if (k < K && excl <= tp){
    val = lv + gumbel_at((uint32_t)b, iv);
    idx = iv;
  }
#pragma unroll
  for (int off = 32; off; off >>= 1){
    float ov = __shfl_down(val, off);
    unsigned oi = __shfl_down(idx, off);
    if (ov > val || (ov == val && oi < idx)){ val = ov; idx = oi; }
  }
  if (k == 0) out_tok[b] = (float)idx;
}

extern "C" void kernel_launch(void* const* d_in, const int* in_sizes, int n_in,
                              void* d_out, int out_size, void* d_ws, size_t ws_size,
                              hipStream_t stream){
  (void)in_sizes; (void)n_in; (void)out_size; (void)ws_size;
  const float* x      = (const float*)d_in[0];
  const float* emb    = (const float*)d_in[1];
  const float* ebias  = (const float*)d_in[2];
  const float* top_ps = (const float*)d_in[3];
  const int*   out_pos= (const int*)d_in[4];
  const int*   top_ks = (const int*)d_in[5];

  float* out    = (float*)d_out;       // [0..63] tokens (as float), then logits [64][V]
  float* logits = out + 64;

  // workspace layout
  unsigned short* hhi = (unsigned short*)d_ws;                    // packed A hi [64][2048] bf16
  unsigned short* hlo = hhi + (size_t)B_ * D_;                    // packed A lo
  char* wp = (char*)d_ws + (size_t)B_ * D_ * 4;                   // after 512KB
  unsigned* Mo   = (unsigned*)wp;          wp += 64 * 4;
  float*    Mb   = (float*)wp;             wp += 64 * 4;
  float*    Zp   = (float*)wp;             wp += 256 * 4;
  unsigned* cnt  = (unsigned*)wp;          wp += 64 * 4;
  unsigned* kef  = (unsigned*)wp;          wp += 64 * 4;
  float*    tv   = (float*)wp;             wp += 64 * 64 * 4;
  unsigned* ti   = (unsigned*)wp;          wp += 64 * 64 * 4;
  float*    cval = (float*)wp;             wp += (size_t)64 * CAND_CAP * 4;
  unsigned* cidx = (unsigned*)wp;          wp += (size_t)64 * CAND_CAP * 4;

  hipLaunchKernelGGL(Sampler_gather,   dim3((B_ * D_ + 255) / 256), dim3(256), 0, stream, x, out_pos, hhi, hlo, cnt, Mo);
  hipLaunchKernelGGL(Sampler_gemm,     dim3(NBLK), dim3(256), 0, stream, hhi, hlo, emb, ebias, logits);
  hipLaunchKernelGGL(Sampler_rowmax,   dim3(256), dim3(256), 0, stream, logits, Mo);
  hipLaunchKernelGGL(Sampler_collectZ, dim3(256), dim3(256), 0, stream, logits, Mo, Mb, Zp, cnt, cval, cidx);
  hipLaunchKernelGGL(Sampler_topk,     dim3(64), dim3(256), 0, stream, cnt, cval, cidx, top_ks, tv, ti, kef);
  hipLaunchKernelGGL(Sampler_sample,   dim3(64), dim3(64), 0, stream, tv, ti, kef, Mb, Zp, top_ps, out);
}

// Round 9
// 427.014 us; speedup vs baseline: 1.2237x; 1.2237x over previous
//
#include <hip/hip_runtime.h>
#include <cstdint>
#include <cstddef>

#define B_ 64
#define S_ 8
#define D_ 2048
#define V_ 128000
#define CAND_CAP 8192
#define BN 128
#define BKF 64             // floats per row per chunk (256B runs)
#define NCH (D_ / BKF)     // 32 chunks
#define NBLK (V_ / BN)     // 1000 blocks

typedef __bf16 v8bf __attribute__((ext_vector_type(8)));
typedef float  v4f  __attribute__((ext_vector_type(4)));

#define GLOBAL_AS __attribute__((address_space(1)))
#define LDS_AS    __attribute__((address_space(3)))

__device__ __forceinline__ void gload_lds16(const float* g, float* l){
  __builtin_amdgcn_global_load_lds((const GLOBAL_AS uint32_t*)g, (LDS_AS uint32_t*)l, 16, 0, 0);
}

// ---------------- threefry2x32 (JAX-compatible) ----------------
__device__ __forceinline__ uint32_t rotl32(uint32_t x, int r){ return (x << r) | (x >> (32 - r)); }
__device__ __forceinline__ void tfround(uint32_t& x0, uint32_t& x1, int r){
  x0 += x1; x1 = rotl32(x1, r); x1 ^= x0;
}
__device__ __forceinline__ void threefry2x32(uint32_t k0, uint32_t k1, uint32_t c0, uint32_t c1,
                                             uint32_t& o0, uint32_t& o1){
  uint32_t ks2 = k0 ^ k1 ^ 0x1BD11BDAu;
  uint32_t x0 = c0 + k0, x1 = c1 + k1;
  tfround(x0,x1,13); tfround(x0,x1,15); tfround(x0,x1,26); tfround(x0,x1,6);
  x0 += k1; x1 += ks2 + 1u;
  tfround(x0,x1,17); tfround(x0,x1,29); tfround(x0,x1,16); tfround(x0,x1,24);
  x0 += ks2; x1 += k0 + 2u;
  tfround(x0,x1,13); tfround(x0,x1,15); tfround(x0,x1,26); tfround(x0,x1,6);
  x0 += k0; x1 += k1 + 3u;
  tfround(x0,x1,17); tfround(x0,x1,29); tfround(x0,x1,16); tfround(x0,x1,24);
  x0 += k1; x1 += ks2 + 4u;
  tfround(x0,x1,13); tfround(x0,x1,15); tfround(x0,x1,26); tfround(x0,x1,6);
  x0 += ks2; x1 += k0 + 5u;
  o0 = x0; o1 = x1;
}

#define JAX_PARTITIONABLE 1

__device__ __forceinline__ float gumbel_at(uint32_t b, uint32_t v){
  uint32_t j = b * (uint32_t)V_ + v;
  uint32_t bits;
#if JAX_PARTITIONABLE
  uint32_t o0, o1; threefry2x32(0u, 42u, 0u, j, o0, o1);
  bits = o0 ^ o1;
#else
  const uint32_t HALF = 4096000u;  // B*V/2
  uint32_t o0, o1;
  if (j < HALF){ threefry2x32(0u, 42u, j, j + HALF, o0, o1); bits = o0; }
  else        { threefry2x32(0u, 42u, j - HALF, j, o0, o1); bits = o1; }
#endif
  uint32_t fb = (bits >> 9) | 0x3F800000u;
  float f = __uint_as_float(fb) - 1.0f;
  const float TINY = 1.17549435e-38f;
  float u = fmaxf(TINY, f + TINY);
  return -logf(-logf(u));
}

__device__ __forceinline__ unsigned ordkey(float f){
  unsigned u = __float_as_uint(f);
  return (u & 0x80000000u) ? ~u : (u | 0x80000000u);
}
__device__ __forceinline__ float ordinv(unsigned o){
  unsigned u = (o & 0x80000000u) ? (o & 0x7FFFFFFFu) : ~o;
  return __uint_as_float(u);
}

__device__ __forceinline__ v8bf ld_bf8(const unsigned short* p){
  uint4 u = *reinterpret_cast<const uint4*>(p);
  return __builtin_bit_cast(v8bf, u);
}

// ---------------- kernels ----------------

// gather h at out_pos, split fp32 -> bf16 hi/lo in FRAGMENT-PACKED layout:
// Apk[(((s*4 + mi)*64) + kg*16 + r16)*8 + j], s = k>>5, kg=(k>>3)&3, j=k&7, mi=b>>4, r16=b&15
__global__ __launch_bounds__(256) void Sampler_gather(const float* __restrict__ x,
    const int* __restrict__ out_pos, unsigned short* __restrict__ hhi,
    unsigned short* __restrict__ hlo, unsigned* __restrict__ cnt,
    unsigned* __restrict__ Mo){
  const int pos = out_pos[0];
  int i = blockIdx.x * 256 + threadIdx.x;
  if (i < B_ * D_){
    int bq = i >> 11;          // b
    int kq = i & 2047;         // k
    float v = x[((size_t)bq * S_ + pos) * D_ + kq];
    __bf16 hb = (__bf16)v;
    float hf = (float)hb;
    __bf16 lb = (__bf16)(v - hf);
    int s  = kq >> 5;
    int kg = (kq >> 3) & 3;
    int j  = kq & 7;
    int mi = bq >> 4;
    int r16 = bq & 15;
    int idx = (((s * 4 + mi) * 64) + kg * 16 + r16) * 8 + j;
    hhi[idx] = __builtin_bit_cast(unsigned short, hb);
    hlo[idx] = __builtin_bit_cast(unsigned short, lb);
  }
  if (i < 64){ cnt[i] = 0; Mo[i] = 0; }
}

// Split-bf16 MFMA GEMM. R6 skeleton, retiled BN=128 x BK=64 (256B DRAM runs per
// emb row per stage). LDS dbuf 2x32KB -> 2 blocks/CU. Wave tile 64M x 32N.
// Swizzle: phys granule = logical ^ (row&15), applied on stage-source and read.
__global__ __launch_bounds__(256, 2) void Sampler_gemm(
    const unsigned short* __restrict__ hhi,  // packed A hi
    const unsigned short* __restrict__ hlo,  // packed A lo
    const float* __restrict__ emb,           // [V_][D_]
    const float* __restrict__ bias,          // [V_]
    float* __restrict__ out)                 // [64][V_]
{
  __shared__ float Bs[2][BN * BKF];          // 2 x 32 KB
  const int tid  = threadIdx.x;
  const int wid  = tid >> 6;
  const int lane = tid & 63;
  const int r16  = lane & 15;
  const int kg   = lane >> 4;                // 0..3
  const int v0   = blockIdx.x * BN;

  // staging: pass p covers rows p*16..p*16+15; thread t -> row p*16 + (t>>4),
  // phys granule t&15, source granule (t&15)^(t>>4)  (row&15 == t>>4).
  const int srow = tid >> 4;                          // 0..15 (+16p)
  const int sg   = (tid & 15) ^ srow;
  const float* sbase = emb + (size_t)(v0 + srow) * D_ + sg * 4;

  v4f acc[4][2];
#pragma unroll
  for (int mi = 0; mi < 4; ++mi)
#pragma unroll
    for (int ni = 0; ni < 2; ++ni) acc[mi][ni] = (v4f){0.f, 0.f, 0.f, 0.f};

  const unsigned short* hhb = hhi + lane * 8;
  const unsigned short* hlb = hlo + lane * 8;

  // prologue: stage chunk 0 (8 passes x 4KB)
#pragma unroll
  for (int p = 0; p < 8; ++p)
    gload_lds16(sbase + (size_t)p * 16 * D_, &Bs[0][p * 1024 + tid * 4]);
  __syncthreads();

#pragma unroll 1
  for (int c = 0; c < NCH; ++c){
    const int cur = c & 1;

    // A fragments for both k-steps of this chunk (s = 2c, 2c+1), issued BEFORE
    // the stage so the compiler's vmcnt wait for A leaves stage loads in flight.
    v8bf ah[2][4], al[2][4];
#pragma unroll
    for (int ks = 0; ks < 2; ++ks)
#pragma unroll
      for (int mi = 0; mi < 4; ++mi){
        const int fo = ((2 * c + ks) * 4 + mi) * 512;
        ah[ks][mi] = ld_bf8(hhb + fo);
        al[ks][mi] = ld_bf8(hlb + fo);
      }

    // stage next chunk
    if (c + 1 < NCH){
#pragma unroll
      for (int p = 0; p < 8; ++p)
        gload_lds16(sbase + (size_t)p * 16 * D_ + (c + 1) * BKF,
                    &Bs[cur ^ 1][p * 1024 + tid * 4]);
    }

    // compute from current buffer
    const float* bbase = &Bs[cur][0];
#pragma unroll
    for (int ks = 0; ks < 2; ++ks){
      const int gI = ks * 8 + 2 * kg;
#pragma unroll
      for (int ni = 0; ni < 2; ++ni){
        const int r = (wid << 5) + (ni << 4) + r16;
        const float* bp = bbase + r * BKF;
        float4 b0 = *(const float4*)(bp + ((gI    ) ^ r16) * 4);  // k = 8kg..+3
        float4 b1 = *(const float4*)(bp + ((gI + 1) ^ r16) * 4);  // k = 8kg+4..+7
        float xf[8] = { b0.x, b0.y, b0.z, b0.w, b1.x, b1.y, b1.z, b1.w };
        v8bf bh, bl;
#pragma unroll
        for (int j = 0; j < 8; ++j){
          float v = xf[j];
          __bf16 hb = (__bf16)v;
          float hf = (float)hb;
          bh[j] = hb;
          bl[j] = (__bf16)(v - hf);
        }
#pragma unroll
        for (int mi = 0; mi < 4; ++mi){
          acc[mi][ni] = __builtin_amdgcn_mfma_f32_16x16x32_bf16(ah[ks][mi], bh, acc[mi][ni], 0, 0, 0);
          acc[mi][ni] = __builtin_amdgcn_mfma_f32_16x16x32_bf16(al[ks][mi], bh, acc[mi][ni], 0, 0, 0);
          acc[mi][ni] = __builtin_amdgcn_mfma_f32_16x16x32_bf16(ah[ks][mi], bl, acc[mi][ni], 0, 0, 0);
        }
      }
    }
    __syncthreads();   // drains vmcnt(0): next buffer complete; LDS WAR safe
  }

  // epilogue: + bias
#pragma unroll
  for (int ni = 0; ni < 2; ++ni){
    const int v = v0 + (wid << 5) + (ni << 4) + r16;
    const float bv = bias[v];
#pragma unroll
    for (int mi = 0; mi < 4; ++mi){
#pragma unroll
      for (int r = 0; r < 4; ++r){
        const int b = 16 * mi + 4 * kg + r;
        out[(size_t)b * V_ + v] = acc[mi][ni][r] + bv;
      }
    }
  }
}

// per-row max via 4 column-slices per row, atomicMax on ordkey
__global__ __launch_bounds__(256) void Sampler_rowmax(const float* __restrict__ logits,
    unsigned* __restrict__ Mo){
  __shared__ float red[4];
  const int b = blockIdx.x >> 2, sl = blockIdx.x & 3;
  const int tid = threadIdx.x;
  const float4* row = (const float4*)(logits + (size_t)b * V_ + sl * 32000);
  float m = -3.4e38f;
  for (int i = tid; i < 8000; i += 256){
    float4 v = row[i];
    m = fmaxf(m, fmaxf(fmaxf(v.x, v.y), fmaxf(v.z, v.w)));
  }
#pragma unroll
  for (int off = 32; off; off >>= 1) m = fmaxf(m, __shfl_down(m, off));
  if ((tid & 63) == 0) red[tid >> 6] = m;
  __syncthreads();
  if (tid == 0){
    m = fmaxf(fmaxf(red[0], red[1]), fmaxf(red[2], red[3]));
    atomicMax(&Mo[b], ordkey(m));
  }
}

// fused: deterministic per-slice softmax-denom partials + atomic-free candidate
// collect (l > M - 1.75) via ballot compaction; one global atomicAdd per block.
__global__ __launch_bounds__(256) void Sampler_collectZ(const float* __restrict__ logits,
    const unsigned* __restrict__ Mo, float* __restrict__ Mb, float* __restrict__ Zp,
    unsigned* __restrict__ cnt, float* __restrict__ cval, unsigned* __restrict__ cidx){
  __shared__ float    sv[4][1024];
  __shared__ unsigned si[4][1024];
  __shared__ unsigned wcnt_s[4];
  __shared__ unsigned gbase_s;
  __shared__ float red[4];
  const int b = blockIdx.x >> 2, sl = blockIdx.x & 3;
  const int tid = threadIdx.x, wid = tid >> 6, lane = tid & 63;
  const float M = ordinv(Mo[b]);
  const float T = M - 1.75f;
  const int base = sl * 32000;
  const float4* row = (const float4*)(logits + (size_t)b * V_ + base);
  unsigned wcnt = 0;
  float z = 0.f;
  for (int i = tid; i < 8000; i += 256){     // 8000 = 31*256 + 64: tails wave-uniform
    float4 v = row[i];
    z += expf(v.x - M); z += expf(v.y - M);
    z += expf(v.z - M); z += expf(v.w - M);
    float vv[4] = {v.x, v.y, v.z, v.w};
    const unsigned idx0 = (unsigned)(base + i * 4);
#pragma unroll
    for (int j = 0; j < 4; ++j){
      bool q = vv[j] > T;
      unsigned long long mask = __ballot(q);
      if (q){
        unsigned slot = wcnt + (unsigned)__popcll(mask & ((1ull << lane) - 1ull));
        if (slot < 1024u){ sv[wid][slot] = vv[j]; si[wid][slot] = idx0 + j; }
      }
      wcnt += (unsigned)__popcll(mask);
    }
  }
  // deterministic Z partial (fixed shuffle order)
#pragma unroll
  for (int off = 32; off; off >>= 1) z += __shfl_down(z, off);
  if (lane == 0){ red[wid] = z; wcnt_s[wid] = wcnt < 1024u ? wcnt : 1024u; }
  __syncthreads();
  if (tid == 0){
    Zp[b * 4 + sl] = ((red[0] + red[1]) + red[2]) + red[3];
    if (sl == 0) Mb[b] = M;
    gbase_s = atomicAdd(&cnt[b], wcnt_s[0] + wcnt_s[1] + wcnt_s[2] + wcnt_s[3]);
  }
  __syncthreads();
  unsigned pre = gbase_s;
  for (int w = 0; w < 4; ++w){ if (w == wid) break; pre += wcnt_s[w]; }
  const unsigned myn = wcnt_s[wid];
  for (unsigned i = lane; i < myn; i += 64){
    unsigned pos = pre + i;
    if (pos < CAND_CAP){
      cval[b * CAND_CAP + pos] = sv[wid][i];
      cidx[b * CAND_CAP + pos] = si[wid][i];
    }
  }
}

// extract top-K (stable: value desc, index asc) by iterative argmax over candidates
__global__ __launch_bounds__(256) void Sampler_topk(const unsigned* __restrict__ cnt,
    const float* __restrict__ cval, const unsigned* __restrict__ cidx,
    const int* __restrict__ top_ks, float* __restrict__ tv, unsigned* __restrict__ ti,
    unsigned* __restrict__ kef){
  __shared__ unsigned long long keys[CAND_CAP];
  __shared__ unsigned long long red[4];
  const int b = blockIdx.x;
  const int tid = threadIdx.x;
  int n = (int)min(cnt[b], (unsigned)CAND_CAP);
  const int nr = (n + 255) & ~255;           // scan bound, multiple of 256
  for (int i = tid; i < nr; i += 256){
    unsigned long long kk = 0ull;
    if (i < n){
      unsigned o = ordkey(cval[b * CAND_CAP + i]);
      kk = ((unsigned long long)o << 32) | (unsigned long long)(0xFFFFFFFFu - cidx[b * CAND_CAP + i]);
    }
    keys[i] = kk;
  }
  __syncthreads();
  int K = top_ks[b];
  K = K < 1 ? 1 : (K > 63 ? 63 : K);
  K = K < n ? K : n;
  for (int k = 0; k < K; ++k){
    unsigned long long best = 0ull;
    for (int i = tid; i < nr; i += 256){
      unsigned long long xx = keys[i];
      best = xx > best ? xx : best;
    }
#pragma unroll
    for (int off = 32; off; off >>= 1){
      unsigned long long o = __shfl_down(best, off);
      best = o > best ? o : best;
    }
    if ((tid & 63) == 0) red[tid >> 6] = best;
    __syncthreads();
    {
      unsigned long long m01 = red[0] > red[1] ? red[0] : red[1];
      unsigned long long m23 = red[2] > red[3] ? red[2] : red[3];
      best = m01 > m23 ? m01 : m23;
    }
    for (int i = tid; i < nr; i += 256)
      if (keys[i] == best) keys[i] = 0ull;
    if (tid == 0){
      tv[b * 64 + k] = ordinv((unsigned)(best >> 32));
      ti[b * 64 + k] = 0xFFFFFFFFu - (unsigned)(best & 0xFFFFFFFFu);
    }
    __syncthreads();
  }
  if (tid == 0) kef[b] = (unsigned)K;
}

// top-p mask on sorted list + gumbel argmax -> token (written as float)
__global__ __launch_bounds__(64) void Sampler_sample(const float* __restrict__ tv,
    const unsigned* __restrict__ ti, const unsigned* __restrict__ kef,
    const float* __restrict__ Mb, const float* __restrict__ Zp,
    const float* __restrict__ top_ps, float* __restrict__ out_tok){
  const int b = blockIdx.x;
  const int k = threadIdx.x;
  const int K = (int)kef[b];
  const float M = Mb[b], tp = top_ps[b];
  const float Z = ((Zp[b * 4 + 0] + Zp[b * 4 + 1]) + Zp[b * 4 + 2]) + Zp[b * 4 + 3];
  float p = 0.f, lv = 0.f; unsigned iv = 0xFFFFFFFFu;
  if (k < K){
    lv = tv[b * 64 + k];
    iv = ti[b * 64 + k];
    p = expf(lv - M) / Z;
  }
  float incl = p;
#pragma unroll
  for (int off = 1; off < 64; off <<= 1){
    float t = __shfl_up(incl, off);
    if (k >= off) incl += t;
  }
  float excl = incl - p;
  float val = -3.4e38f; unsigned idx = 0xFFFFFFFFu;
  if (k < K && excl <= tp){
    val = lv + gumbel_at((uint32_t)b, iv);
    idx = iv;
  }
#pragma unroll
  for (int off = 32; off; off >>= 1){
    float ov = __shfl_down(val, off);
    unsigned oi = __shfl_down(idx, off);
    if (ov > val || (ov == val && oi < idx)){ val = ov; idx = oi; }
  }
  if (k == 0) out_tok[b] = (float)idx;
}

extern "C" void kernel_launch(void* const* d_in, const int* in_sizes, int n_in,
                              void* d_out, int out_size, void* d_ws, size_t ws_size,
                              hipStream_t stream){
  (void)in_sizes; (void)n_in; (void)out_size; (void)ws_size;
  const float* x      = (const float*)d_in[0];
  const float* emb    = (const float*)d_in[1];
  const float* ebias  = (const float*)d_in[2];
  const float* top_ps = (const float*)d_in[3];
  const int*   out_pos= (const int*)d_in[4];
  const int*   top_ks = (const int*)d_in[5];

  float* out    = (float*)d_out;       // [0..63] tokens (as float), then logits [64][V]
  float* logits = out + 64;

  // workspace layout
  unsigned short* hhi = (unsigned short*)d_ws;                    // packed A hi [64][2048] bf16
  unsigned short* hlo = hhi + (size_t)B_ * D_;                    // packed A lo
  char* wp = (char*)d_ws + (size_t)B_ * D_ * 4;                   // after 512KB
  unsigned* Mo   = (unsigned*)wp;          wp += 64 * 4;
  float*    Mb   = (float*)wp;             wp += 64 * 4;
  float*    Zp   = (float*)wp;             wp += 256 * 4;
  unsigned* cnt  = (unsigned*)wp;          wp += 64 * 4;
  unsigned* kef  = (unsigned*)wp;          wp += 64 * 4;
  float*    tv   = (float*)wp;             wp += 64 * 64 * 4;
  unsigned* ti   = (unsigned*)wp;          wp += 64 * 64 * 4;
  float*    cval = (float*)wp;             wp += (size_t)64 * CAND_CAP * 4;
  unsigned* cidx = (unsigned*)wp;          wp += (size_t)64 * CAND_CAP * 4;

  hipLaunchKernelGGL(Sampler_gather,   dim3((B_ * D_ + 255) / 256), dim3(256), 0, stream, x, out_pos, hhi, hlo, cnt, Mo);
  hipLaunchKernelGGL(Sampler_gemm,     dim3(NBLK), dim3(256), 0, stream, hhi, hlo, emb, ebias, logits);
  hipLaunchKernelGGL(Sampler_rowmax,   dim3(256), dim3(256), 0, stream, logits, Mo);
  hipLaunchKernelGGL(Sampler_collectZ, dim3(256), dim3(256), 0, stream, logits, Mo, Mb, Zp, cnt, cval, cidx);
  hipLaunchKernelGGL(Sampler_topk,     dim3(64), dim3(256), 0, stream, cnt, cval, cidx, top_ks, tv, ti, kef);
  hipLaunchKernelGGL(Sampler_sample,   dim3(64), dim3(64), 0, stream, tv, ti, kef, Mb, Zp, top_ps, out);
}